// Round 2
// baseline (576.507 us; speedup 1.0000x reference)
//
#include <hip/hip_runtime.h>

typedef _Float16 f16;
typedef _Float16 f16x8 __attribute__((ext_vector_type(8)));
typedef _Float16 f16x4 __attribute__((ext_vector_type(4)));
typedef float    f32x4 __attribute__((ext_vector_type(4)));

static constexpr int H  = 128;   // hidden width
static constexpr int MT = 128;   // edges per block
static constexpr int PC = 40;    // k-chunk row stride in halves (32 + 8 pad)
static constexpr int PA = 136;   // act row stride in halves (128 + 8 pad)

__global__ __launch_bounds__(256, 2)
void edge_mlp_fused(const float* __restrict__ x,
                    const int* __restrict__ eidx,     // int32 on device (harness contract)
                    const float* __restrict__ edge,
                    const float* __restrict__ W0, const float* __restrict__ b0,
                    const float* __restrict__ g0, const float* __restrict__ be0,
                    const float* __restrict__ W1, const float* __restrict__ b1,
                    const float* __restrict__ g1, const float* __restrict__ be1,
                    const float* __restrict__ W2, const float* __restrict__ b2,
                    const float* __restrict__ g2, const float* __restrict__ be2,
                    const float* __restrict__ W3, const float* __restrict__ b3,
                    float* __restrict__ out, int E)
{
    __shared__ f16   achunk[MT * PC];   // A tile k-chunk (f16)
    __shared__ f16   wchunk[H * PC];    // W^T k-chunk (f16): [n][k]
    __shared__ f16   act[MT * PA];      // activations between layers
    __shared__ int   srcoff[MT];
    __shared__ int   dstoff[MT];
    __shared__ float outbuf[MT];

    const int tid  = threadIdx.x;
    const int lane = tid & 63;
    const int wid  = tid >> 6;
    const int c    = lane & 15;   // MFMA "16-dim" lane coord
    const int g    = lane >> 4;   // quad group 0..3
    const int wrow = wid * 32;    // this wave's first local edge row
    const long long e0 = (long long)blockIdx.x * MT;

    // stage gather byte-offsets
    if (tid < MT) {
        long long e = e0 + tid; if (e >= E) e = (long long)E - 1;
        srcoff[tid] = eidx[e]     * (H * 4);
        dstoff[tid] = eidx[E + e] * (H * 4);
    }

    f32x4 acc[8][2];
    #pragma unroll
    for (int t = 0; t < 8; ++t) {
        acc[t][0] = f32x4{0.f, 0.f, 0.f, 0.f};
        acc[t][1] = f32x4{0.f, 0.f, 0.f, 0.f};
    }

    // stage 32 k-rows of W (K x 128, row-major) transposed into wchunk[n][k], f16
    auto stageW = [&](const float* __restrict__ W, int k0) {
        #pragma unroll
        for (int i = 0; i < 4; ++i) {
            int f  = i * 256 + tid;          // 0..1023 = 128 n x 8 kquads
            int n  = f & 127;
            int kq = f >> 7;                 // 0..7
            const float* p = W + (size_t)(k0 + kq * 4) * H + n;
            f16x4 v;
            v[0] = (f16)p[0];
            v[1] = (f16)p[H];
            v[2] = (f16)p[2 * H];
            v[3] = (f16)p[3 * H];
            *(f16x4*)&wchunk[n * PC + kq * 4] = v;   // 8B contiguous write
        }
    };

    // one K=32 step: 16 MFMAs against current wchunk
    auto mfma_tiles = [&](const f16* __restrict__ A, int astride, int koff) {
        f16x8 a0 = *(const f16x8*)&A[(wrow + c)      * astride + koff + g * 8];
        f16x8 a1 = *(const f16x8*)&A[(wrow + 16 + c) * astride + koff + g * 8];
        #pragma unroll
        for (int t = 0; t < 8; ++t) {
            f16x8 bf = *(const f16x8*)&wchunk[(t * 16 + c) * PC + g * 8];
            acc[t][0] = __builtin_amdgcn_mfma_f32_16x16x32_f16(a0, bf, acc[t][0], 0, 0, 0);
            acc[t][1] = __builtin_amdgcn_mfma_f32_16x16x32_f16(a1, bf, acc[t][1], 0, 0, 0);
        }
    };

    // LayerNorm(+bias,gamma,beta)+ReLU on acc, write f16 act, reset acc
    auto ln_relu_store = [&](const float* __restrict__ bias,
                             const float* __restrict__ gamma,
                             const float* __restrict__ beta) {
        float mu[2][4], rs[2][4];
        #pragma unroll
        for (int t = 0; t < 8; ++t) {
            float bt = bias[t * 16 + c];
            #pragma unroll
            for (int s = 0; s < 2; ++s)
                #pragma unroll
                for (int r = 0; r < 4; ++r) acc[t][s][r] += bt;
        }
        #pragma unroll
        for (int s = 0; s < 2; ++s)
            #pragma unroll
            for (int r = 0; r < 4; ++r) {
                float v = 0.f, q = 0.f;
                #pragma unroll
                for (int t = 0; t < 8; ++t) { float a = acc[t][s][r]; v += a; q += a * a; }
                #pragma unroll
                for (int m = 1; m < 16; m <<= 1) {
                    v += __shfl_xor(v, m, 64);
                    q += __shfl_xor(q, m, 64);
                }
                float mean = v * (1.0f / H);
                float var  = q * (1.0f / H) - mean * mean;
                mu[s][r] = mean;
                rs[s][r] = rsqrtf(var + 1e-5f);
            }
        __syncthreads();   // previous GEMM's act readers must finish before overwrite
        #pragma unroll
        for (int t = 0; t < 8; ++t) {
            float gm = gamma[t * 16 + c];
            float bb = beta[t * 16 + c];
            #pragma unroll
            for (int s = 0; s < 2; ++s)
                #pragma unroll
                for (int r = 0; r < 4; ++r) {
                    float v = (acc[t][s][r] - mu[s][r]) * rs[s][r] * gm + bb;
                    v = fmaxf(v, 0.f);
                    act[(wrow + s * 16 + g * 4 + r) * PA + t * 16 + c] = (f16)v;
                }
        }
        #pragma unroll
        for (int t = 0; t < 8; ++t) {
            acc[t][0] = f32x4{0.f, 0.f, 0.f, 0.f};
            acc[t][1] = f32x4{0.f, 0.f, 0.f, 0.f};
        }
    };

    // ---------------- GEMM1: concat(x[src],x[dst],edge) @ W0, K=384 ----------------
    for (int kc = 0; kc < 12; ++kc) {
        __syncthreads();
        {   // stage A chunk: 128 rows x 32 k (f32 -> f16)
            int r  = tid >> 1;
            int hf = tid & 1;
            int kk = (kc & 3) * 32 + hf * 16;
            const float* p;
            if (kc < 4)      p = (const float*)((const char*)x + srcoff[r]) + kk;
            else if (kc < 8) p = (const float*)((const char*)x + dstoff[r]) + kk;
            else {
                long long e = e0 + r; if (e >= E) e = (long long)E - 1;
                p = edge + e * H + kk;
            }
            float4 v0 = ((const float4*)p)[0];
            float4 v1 = ((const float4*)p)[1];
            float4 v2 = ((const float4*)p)[2];
            float4 v3 = ((const float4*)p)[3];
            f16x8 lo, hi;
            lo[0] = (f16)v0.x; lo[1] = (f16)v0.y; lo[2] = (f16)v0.z; lo[3] = (f16)v0.w;
            lo[4] = (f16)v1.x; lo[5] = (f16)v1.y; lo[6] = (f16)v1.z; lo[7] = (f16)v1.w;
            hi[0] = (f16)v2.x; hi[1] = (f16)v2.y; hi[2] = (f16)v2.z; hi[3] = (f16)v2.w;
            hi[4] = (f16)v3.x; hi[5] = (f16)v3.y; hi[6] = (f16)v3.z; hi[7] = (f16)v3.w;
            *(f16x8*)&achunk[r * PC + hf * 16]     = lo;
            *(f16x8*)&achunk[r * PC + hf * 16 + 8] = hi;
        }
        stageW(W0, kc * 32);
        __syncthreads();
        mfma_tiles(achunk, PC, 0);
    }
    ln_relu_store(b0, g0, be0);

    // ---------------- GEMM2: act @ W1, K=128 ----------------
    for (int kc = 0; kc < 4; ++kc) {
        __syncthreads();
        stageW(W1, kc * 32);
        __syncthreads();
        mfma_tiles(act, PA, kc * 32);
    }
    ln_relu_store(b1, g1, be1);

    // ---------------- GEMM3: act @ W2, K=128 ----------------
    for (int kc = 0; kc < 4; ++kc) {
        __syncthreads();
        stageW(W2, kc * 32);
        __syncthreads();
        mfma_tiles(act, PA, kc * 32);
    }

    // ---------------- layer-3 LN+ReLU fused with final dot(W3)+b3 ----------------
    {
        float mu[2][4], rs[2][4];
        #pragma unroll
        for (int t = 0; t < 8; ++t) {
            float bt = b2[t * 16 + c];
            #pragma unroll
            for (int s = 0; s < 2; ++s)
                #pragma unroll
                for (int r = 0; r < 4; ++r) acc[t][s][r] += bt;
        }
        #pragma unroll
        for (int s = 0; s < 2; ++s)
            #pragma unroll
            for (int r = 0; r < 4; ++r) {
                float v = 0.f, q = 0.f;
                #pragma unroll
                for (int t = 0; t < 8; ++t) { float a = acc[t][s][r]; v += a; q += a * a; }
                #pragma unroll
                for (int m = 1; m < 16; m <<= 1) {
                    v += __shfl_xor(v, m, 64);
                    q += __shfl_xor(q, m, 64);
                }
                float mean = v * (1.0f / H);
                float var  = q * (1.0f / H) - mean * mean;
                mu[s][r] = mean;
                rs[s][r] = rsqrtf(var + 1e-5f);
            }
        float po[2][4] = {{0.f,0.f,0.f,0.f},{0.f,0.f,0.f,0.f}};
        #pragma unroll
        for (int t = 0; t < 8; ++t) {
            float gm  = g2[t * 16 + c];
            float bb  = be2[t * 16 + c];
            float w3v = W3[t * 16 + c];
            #pragma unroll
            for (int s = 0; s < 2; ++s)
                #pragma unroll
                for (int r = 0; r < 4; ++r) {
                    float v = (acc[t][s][r] - mu[s][r]) * rs[s][r] * gm + bb;
                    v = fmaxf(v, 0.f);
                    po[s][r] += v * w3v;
                }
        }
        #pragma unroll
        for (int s = 0; s < 2; ++s)
            #pragma unroll
            for (int r = 0; r < 4; ++r) {
                #pragma unroll
                for (int m = 1; m < 16; m <<= 1) po[s][r] += __shfl_xor(po[s][r], m, 64);
            }
        if (c == 0) {
            #pragma unroll
            for (int s = 0; s < 2; ++s)
                #pragma unroll
                for (int r = 0; r < 4; ++r)
                    outbuf[wrow + s * 16 + g * 4 + r] = po[s][r];
        }
    }
    __syncthreads();
    if (tid < MT) {
        long long e = e0 + tid;
        if (e < E) out[e] = outbuf[tid] + b3[0];
    }
}

extern "C" void kernel_launch(void* const* d_in, const int* in_sizes, int n_in,
                              void* d_out, int out_size, void* d_ws, size_t ws_size,
                              hipStream_t stream)
{
    const float* x    = (const float*)d_in[0];
    const int*   eidx = (const int*)d_in[1];     // int64 in reference -> int32 on device
    const float* edge = (const float*)d_in[2];
    const float* W0   = (const float*)d_in[3];
    const float* b0   = (const float*)d_in[4];
    const float* g0   = (const float*)d_in[5];
    const float* be0  = (const float*)d_in[6];
    const float* W1   = (const float*)d_in[7];
    const float* b1   = (const float*)d_in[8];
    const float* g1   = (const float*)d_in[9];
    const float* be1  = (const float*)d_in[10];
    const float* W2   = (const float*)d_in[11];
    const float* b2   = (const float*)d_in[12];
    const float* g2   = (const float*)d_in[13];
    const float* be2  = (const float*)d_in[14];
    const float* W3   = (const float*)d_in[15];
    const float* b3   = (const float*)d_in[16];
    float*       out  = (float*)d_out;

    const int E = in_sizes[1] / 2;           // edge_index is (2, E)
    const int grid = (E + MT - 1) / MT;

    hipLaunchKernelGGL(edge_mlp_fused, dim3(grid), dim3(256), 0, stream,
                       x, eidx, edge,
                       W0, b0, g0, be0,
                       W1, b1, g1, be1,
                       W2, b2, g2, be2,
                       W3, b3, out, E);
}